// Round 22
// baseline (92.929 us; speedup 1.0000x reference)
//
#include <hip/hip_runtime.h>
#include <math.h>

#define PI_F      3.141592653f
#define TWO_PI_F  6.283185306f
#define HALF_PI_F 1.5707963265f
#define IOU_THR_F 0.1f

typedef unsigned long long u64;

__device__ __forceinline__ float limit_period_f(float v) {
    return v - floorf(v / TWO_PI_F + 0.5f) * TWO_PI_F;
}

// ---------------- Kernel 1: adjacency + occByte + validArr zero-init ----------
__global__ void adj_kernel(const float* __restrict__ boxes,
                           u64* __restrict__ adjC,
                           unsigned char* __restrict__ occByte,
                           int* __restrict__ validArr,
                           int n, int words) {
    __shared__ float jS[7][64];
    int w = blockIdx.x;
    int tid = threadIdx.x;              // 256 = 4 waves
    int lane = tid & 63, wv = tid >> 6;
    if (blockIdx.x == 0) {
        int i2 = blockIdx.y * 256 + tid;
        if (i2 < n) validArr[i2] = 0;
    }
    if (tid < 64) {
        int j = (w << 6) + tid;
        if (j < n) {
            float b0 = boxes[j*7+0], b1 = boxes[j*7+1], b2 = boxes[j*7+2];
            float b3 = boxes[j*7+3], b4 = boxes[j*7+4], b5 = boxes[j*7+5];
            jS[0][tid] = b0 - b5*0.5f;  jS[3][tid] = b0 + b5*0.5f;
            jS[1][tid] = b1 - b4*0.5f;  jS[4][tid] = b1 + b4*0.5f;
            jS[2][tid] = b2 - b3*0.5f;  jS[5][tid] = b2 + b3*0.5f;
            jS[6][tid] = (b5*b4)*b3;
        }
    }
    __syncthreads();
    int i = blockIdx.y * 256 + tid;
    u64 word = 0ull;
    if (i < n) {
        float b0 = boxes[i*7+0], b1 = boxes[i*7+1], b2 = boxes[i*7+2];
        float b3 = boxes[i*7+3], b4 = boxes[i*7+4], b5 = boxes[i*7+5];
        float lix = b0 - b5*0.5f, hix = b0 + b5*0.5f;
        float liy = b1 - b4*0.5f, hiy = b1 + b4*0.5f;
        float liz = b2 - b3*0.5f, hiz = b2 + b3*0.5f;
        float vi  = (b5*b4)*b3;
        int jmax = n - (w << 6); if (jmax > 64) jmax = 64;
        for (int jj = 0; jj < jmax; ++jj) {
            float ix = fminf(hix, jS[3][jj]) - fmaxf(lix, jS[0][jj]); ix = fmaxf(ix, 0.0f);
            float iy = fminf(hiy, jS[4][jj]) - fmaxf(liy, jS[1][jj]); iy = fmaxf(iy, 0.0f);
            float iz = fminf(hiz, jS[5][jj]) - fmaxf(liz, jS[2][jj]); iz = fmaxf(iz, 0.0f);
            float inter = (ix*iy)*iz;
            float u = fmaxf(vi + jS[6][jj] - inter, 1e-8f);
            bool pred = (inter / u) > IOU_THR_F;
            word |= ((u64)(pred ? 1 : 0)) << jj;
        }
        adjC[(size_t)w * n + i] = word;
    }
    u64 bal = __ballot((i < n) && word != 0ull);
    int rb = blockIdx.y * 4 + wv;
    if (lane == 0 && rb < 64)
        occByte[rb * 64 + w] = bal ? (unsigned char)1 : (unsigned char)0;
}

// ---------------- Kernel 2: MIS rounds w/ inline coalesced gather (1 block) ---
// (R16-validated round logic; R18-validated gather.) seed(i) <=> no earlier
// neighbor of i is a seed. Thread tid's slot-k node lives in row-block
// rb=(k<<4)+wv (wave-uniform) so (rb,e)-pair loads are coalesced across lanes.
// Rounds touch only LDS bitsets + registers. Emits final seed bitset S[64].
__global__ __launch_bounds__(1024) void mis_round_kernel(
        const u64* __restrict__ adjC,
        const unsigned char* __restrict__ occByte,
        u64* __restrict__ SG, int n, int words) {
    __shared__ u64 S_l[64], R_l[64], occL[64];
    __shared__ int unresolved;
    int tid = threadIdx.x;              // 1024 = 16 waves
    int lane = tid & 63, wv = tid >> 6;

    for (int rb = wv; rb < 64; rb += 16) {
        unsigned char b = occByte[rb * 64 + lane];
        u64 m = __ballot(b != 0);
        if (lane == 0) occL[rb] = m;
    }
    if (tid < 64) {
        int base = tid << 6;
        int vb = n - base;
        u64 valid = (vb >= 64) ? ~0ull : ((vb <= 0) ? 0ull : ((1ull << vb) - 1ull));
        S_l[tid] = 0ull;
        R_l[tid] = ~valid;              // invalid tail = resolved nonseed
    }
    __syncthreads();

    // inline coalesced gather: earlier-masked rows into static register slots
    int id0[4], id1[4], id2[4], id3[4];
    u64 r0[4], r1[4], r2[4], r3[4], rstR[4];
    #pragma unroll
    for (int k = 0; k < 4; ++k) {
        int rb = (k << 4) + wv;         // wave-uniform row-block of this slot
        int i = (rb << 6) + lane;
        id0[k] = id1[k] = id2[k] = id3[k] = 0xFF;
        r0[k] = r1[k] = r2[k] = r3[k] = 0ull; rstR[k] = 0ull;
        u64 lowm = lane ? ((1ull << lane) - 1ull) : 0ull;
        u64 oc = occL[rb] & ((rb >= 63) ? ~0ull : ((2ull << rb) - 1ull));
        int cnt = 0;
        while (oc) {
            int e = (int)__ffsll(oc) - 1; oc &= oc - 1;
            if (e >= words) break;
            u64 row = (i < n) ? adjC[(size_t)e * n + i] : 0ull;   // coalesced
            u64 em = (e < rb) ? ~0ull : lowm;
            u64 re = row & em;
            if (re) {
                if      (cnt == 0) { id0[k] = e; r0[k] = re; }
                else if (cnt == 1) { id1[k] = e; r1[k] = re; }
                else if (cnt == 2) { id2[k] = e; r2[k] = re; }
                else if (cnt == 3) { id3[k] = e; r3[k] = re; }
                else rstR[k] |= 1ull << e;
                ++cnt;
            }
        }
    }

    unsigned done = 0;
    #pragma unroll
    for (int k = 0; k < 4; ++k)
        if ((((k << 4) + wv) << 6) + lane >= n) done |= 1u << k;

    for (;;) {
        if (tid == 0) unresolved = 0;
        unsigned pendSeed = 0, pendRes = 0;
        #pragma unroll
        for (int k = 0; k < 4; ++k) {
            if (done & (1u << k)) continue;
            int rb = (k << 4) + wv;
            int i = (rb << 6) + lane;
            u64 lowm = lane ? ((1ull << lane) - 1ull) : 0ull;
            u64 sA = 0ull, uA = 0ull;
            if (id0[k] != 0xFF) { sA |= r0[k] & S_l[id0[k]]; uA |= r0[k] & ~R_l[id0[k]]; }
            if (id1[k] != 0xFF) { sA |= r1[k] & S_l[id1[k]]; uA |= r1[k] & ~R_l[id1[k]]; }
            if (id2[k] != 0xFF) { sA |= r2[k] & S_l[id2[k]]; uA |= r2[k] & ~R_l[id2[k]]; }
            if (id3[k] != 0xFF) { sA |= r3[k] & S_l[id3[k]]; uA |= r3[k] & ~R_l[id3[k]]; }
            u64 rm = rstR[k];
            while (rm) {
                int e = (int)__ffsll(rm) - 1; rm &= rm - 1;
                u64 row = adjC[(size_t)e * n + i];
                u64 em = (e < rb) ? ~0ull : lowm;
                sA |= row & S_l[e] & em;
                uA |= row & ~R_l[e] & em;
            }
            if (sA) pendRes |= 1u << k;
            else if (!uA) { pendSeed |= 1u << k; pendRes |= 1u << k; }
        }
        __syncthreads();
        #pragma unroll
        for (int k = 0; k < 4; ++k) {
            u64 bS = __ballot((pendSeed >> k) & 1u);
            u64 bR = __ballot((pendRes  >> k) & 1u);
            int rb = (k << 4) + wv;
            if (lane == 0 && rb < 64) {
                if (bS) atomicOr(&S_l[rb], bS);
                if (bR) atomicOr(&R_l[rb], bR);
            }
        }
        done |= pendRes;
        if ((done & 0xFu) != 0xFu) unresolved = 1;
        __syncthreads();
        if (unresolved == 0) break;
    }
    if (tid < 64) SG[tid] = S_l[tid];
}

// ---------------- Kernel 3: indices + seedList + nclust (occ-guided) ----------
// indices[j] = rank of max-index adjacent seed (last-writer-wins semantics):
// ascending scan keeping last nonzero (R16-validated). Coalesced reads.
__global__ __launch_bounds__(64) void indices_kernel(
        const u64* __restrict__ adjC,
        const unsigned char* __restrict__ occByte,
        const u64* __restrict__ SG,
        int* __restrict__ indices, int* __restrict__ seedList,
        int* __restrict__ nclust, int n, int words) {
    __shared__ u64 S_s[64];
    __shared__ int ws_s[64];
    int rb = blockIdx.x;           // 64 row-blocks
    int lane = threadIdx.x;        // 64 = 1 wave
    unsigned char ob = occByte[rb * 64 + lane];
    u64 occR = __ballot(ob != 0);  // occupied words of this row-block (uniform)
    u64 s = (lane < words) ? SG[lane] : 0ull;
    S_s[lane] = s;
    int pc = (int)__popcll(s);
    int x = pc;
    for (int o = 1; o < 64; o <<= 1) {
        int y = __shfl_up(x, o);
        if (lane >= o) x += y;
    }
    ws_s[lane] = x - pc;           // exclusive scan
    if (rb == 0 && lane == 63) *nclust = x;
    __syncthreads();
    int j = (rb << 6) + lane;
    if (j >= n) return;
    int best = -1;
    u64 oc = occR;
    while (oc) {
        int e = (int)__ffsll(oc) - 1; oc &= oc - 1;
        if (e >= words) break;
        u64 m2 = adjC[(size_t)e * n + j] & S_s[e];   // coalesced across j
        if (m2) best = (e << 6) + 63 - (int)__clzll(m2);   // last nonzero = max
    }
    int idx = 0;
    if (best >= 0) {
        int w2 = best >> 6, b = best & 63;
        u64 incl = (b >= 63) ? ~0ull : ((2ull << b) - 1ull);
        idx = ws_s[w2] + (int)__popcll(S_s[w2] & incl);   // 1-based cid
    }
    indices[j] = idx;
    int bj = j & 63;
    if ((S_s[rb] >> bj) & 1ull) {
        int rank = ws_s[rb] + (int)__popcll(S_s[rb] & (bj ? ((1ull << bj) - 1ull) : 0ull)) + 1;
        seedList[rank - 1] = j;
    }
}

// ---------------- Kernel 4: per-cluster fusion (LDS-staged, phase-split) ------
// Loops only over real clusters (i < nclust); rows >= nclust need nothing:
// validArr zero-initialized in adj, and finalize gates all reads on validS.
__global__ void fusion_kernel(const float* __restrict__ boxes,
                              const float* __restrict__ scores,
                              const int* __restrict__ indices,
                              const int* __restrict__ seedListG,
                              const int* __restrict__ nclust,
                              const u64* __restrict__ adjC,
                              float* __restrict__ fused,
                              float* __restrict__ sfused,
                              int* __restrict__ validArr, int n, int words) {
    int lane = threadIdx.x;       // 64 = 1 wave
    int nc = *nclust;
    __shared__ unsigned short js[256];
    __shared__ float ms[256];
    __shared__ float ds[256];
    __shared__ float bx[6][256];
    __shared__ float sv[256], cv[256], pw[256];
    __shared__ float refdirS, denomS;
    __shared__ int   flipS;
    for (int i = blockIdx.x; i < nc; i += gridDim.x) {
        int cid = i + 1;
        int s = seedListG[i];
        u64 bits = (lane < words) ? adjC[(size_t)lane * n + s] : 0ull;
        // filter: keep only nodes whose final cluster is cid
        u64 keep = 0ull;
        u64 t = bits;
        while (t) {
            int b = (int)__ffsll(t) - 1;
            t &= t - 1;
            int node = (lane << 6) + b;
            if (indices[node] == cid) keep |= (1ull << b);
        }
        int cnt = __popcll(keep);
        int x = cnt;
        for (int o = 1; o < 64; o <<= 1) {
            int y = __shfl_up(x, o);
            if (lane >= o) x += y;
        }
        int excl = x - cnt;
        int m = __shfl(x, 63);
        int pos = excl;
        t = keep;
        while (t) {
            int b = (int)__ffsll(t) - 1;
            t &= t - 1;
            js[pos++] = (unsigned short)((lane << 6) + b);
        }
        __syncthreads();
        for (int k = lane; k < m; k += 64) {
            int j = js[k];
            ms[k] = scores[j];
            ds[k] = limit_period_f(boxes[j*7+6]);
            bx[0][k] = boxes[j*7+0];
            bx[1][k] = boxes[j*7+1];
            bx[2][k] = boxes[j*7+2];
            bx[3][k] = boxes[j*7+3];
            bx[4][k] = boxes[j*7+4];
            bx[5][k] = boxes[j*7+5];
        }
        __syncthreads();
        if (m == 0) {
            if (lane == 0) {
                for (int k = 0; k < 7; ++k) fused[i*7+k] = 0.0f;
                sfused[i] = 0.0f; validArr[i] = 0;
            }
            __syncthreads();
            continue;
        }
        // ---- phase A (lane 0, LDS-only): ssum/argmax/refdir/denom/flip ----
        if (lane == 0) {
            float ssum = 0.0f, smax = -1e30f; int kref = 0;
            for (int k = 0; k < m; ++k) {
                float sc = ms[k];
                ssum += sc;
                if (sc > smax) { smax = sc; kref = k; }
            }
            float refdir = ds[kref];
            float denom = fmaxf(ssum, 1e-12f);
            float sgt = 0.0f;
            for (int k = 0; k < m; ++k) {
                float d = fabsf(ds[k] - refdir);
                if (d > PI_F) d = TWO_PI_F - d;
                if (d > HALF_PI_F) sgt += ms[k];
            }
            float sle = ssum - sgt;
            refdirS = refdir; denomS = denom;
            flipS = (sgt <= sle) ? 1 : 0;
        }
        __syncthreads();
        // ---- phase B (parallel): per-element trig ----
        {
            float refdir = refdirS, denom = denomS;
            bool flipGt = flipS != 0;
            for (int k = lane; k < m; k += 64) {
                float dj = ds[k];
                float d = fabsf(dj - refdir);
                if (d > PI_F) d = TWO_PI_F - d;
                bool gt = d > HALF_PI_F;
                bool flip = flipGt ? gt : !gt;
                float adj_d = limit_period_f(dj + (flip ? PI_F : 0.0f));
                float wgt = ms[k] / denom;
                sv[k] = sinf(adj_d) * wgt;
                cv[k] = cosf(adj_d) * wgt;
            }
        }
        __syncthreads();
        // ---- phase C (lane 0): weighted sums + theta + sort ----
        if (lane == 0) {
            float denom = denomS;
            float cd0=0,cd1=0,cd2=0,cd3=0,cd4=0,cd5=0;
            for (int k = 0; k < m; ++k) {
                float wgt = ms[k] / denom;
                cd0 += wgt * bx[0][k];
                cd1 += wgt * bx[1][k];
                cd2 += wgt * bx[2][k];
                cd3 += wgt * bx[3][k];
                cd4 += wgt * bx[4][k];
                cd5 += wgt * bx[5][k];
            }
            float ssin = 0.0f, scos = 0.0f;
            for (int k = 0; k < m; ++k) { ssin += sv[k]; scos += cv[k]; }
            float theta = atan2f(ssin, scos);
            for (int k = 1; k < m; ++k) {
                float key = ms[k]; int p = k - 1;
                while (p >= 0 && ms[p] < key) { ms[p+1] = ms[p]; --p; }
                ms[p+1] = key;
            }
            bx[0][255] = cd0; bx[1][255] = cd1; bx[2][255] = cd2;
            bx[3][255] = cd3; bx[4][255] = cd4; bx[5][255] = cd5;
            sv[255] = theta;
        }
        __syncthreads();
        // ---- phase D (parallel): powf on sorted scores ----
        for (int k = lane; k < m; k += 64)
            pw[k] = powf(ms[k], (float)(k+1));
        __syncthreads();
        // ---- phase E (lane 0): s_fused + corners + writes ----
        if (lane == 0) {
            float cd0 = bx[0][255], cd1 = bx[1][255], cd2 = bx[2][255];
            float cd3 = bx[3][255], cd4 = bx[4][255], cd5 = bx[5][255];
            float theta = sv[255];
            float sf = 0.0f;
            for (int k = 0; k < m; ++k) sf += pw[k];
            sf = fminf(sf, 1.0f);
            float c_ = cosf(theta), s_ = sinf(theta);
            float wdim = cd4, ldim = cd5;
            const float xs[4]  = {0.5f, 0.5f, -0.5f, -0.5f};
            const float ys_[4] = {-0.5f, 0.5f, 0.5f, -0.5f};
            bool inr = true;
            for (int c = 0; c < 4; ++c) {
                float cx = ldim * xs[c], cy = wdim * ys_[c];
                float rx = cx*c_ - cy*s_ + cd0;
                float ry = cx*s_ + cy*c_ + cd1;
                inr = inr && (rx > -140.8f) && (rx < 140.8f) && (ry > -40.0f) && (ry < 40.0f);
            }
            fused[i*7+0]=cd0; fused[i*7+1]=cd1; fused[i*7+2]=cd2;
            fused[i*7+3]=cd3; fused[i*7+4]=cd4; fused[i*7+5]=cd5;
            fused[i*7+6]=theta;
            sfused[i] = sf;
            validArr[i] = inr ? 1 : 0;
        }
        __syncthreads();
    }
}

// ---------------- Kernel 5: cumsum + gated output writes ----------------
__global__ void finalize_kernel(const float* __restrict__ fused,
                                const float* __restrict__ sfused,
                                const int* __restrict__ validArr,
                                const int* __restrict__ indices,
                                float* __restrict__ out, int n) {
    __shared__ int newidS[4096];
    __shared__ unsigned char validS[4096];
    __shared__ int scanBuf[1024];
    int tid = threadIdx.x;  // 1024
    int per = (n + 1023) >> 10;  // 4
    int base = tid * per;
    int v[8];
    int sum = 0;
    for (int k = 0; k < per && k < 8; ++k) {
        int j = base + k;
        int vv = (j < n) ? validArr[j] : 0;
        v[k] = vv; sum += vv;
    }
    scanBuf[tid] = sum;
    __syncthreads();
    for (int o = 1; o < 1024; o <<= 1) {
        int val = scanBuf[tid];
        int add = (tid >= o) ? scanBuf[tid - o] : 0;
        __syncthreads();
        scanBuf[tid] = val + add;
        __syncthreads();
    }
    int run = scanBuf[tid] - sum;
    for (int k = 0; k < per && k < 8; ++k) {
        int j = base + k;
        if (j < n) { run += v[k]; newidS[j] = run; validS[j] = (unsigned char)v[k]; }
    }
    __syncthreads();
    float* boxesO  = out;
    float* scoresO = out + (size_t)7*n;
    float* validO  = out + (size_t)8*n;
    float* idxO    = out + (size_t)9*n;
    for (int j = tid; j < n; j += 1024) {
        int vv = validS[j];
        #pragma unroll
        for (int k = 0; k < 7; ++k)
            boxesO[j*7+k] = vv ? fused[j*7+k] : 0.0f;
        scoresO[j] = vv ? sfused[j] : 0.0f;
        validO[j]  = vv ? 1.0f : 0.0f;
        int ind = indices[j];
        int safe = ind - 1; if (safe < 0) safe = 0;
        bool nv = (ind > 0) && (validS[safe] != 0);
        idxO[j] = nv ? (float)newidS[safe] : 0.0f;
    }
}

extern "C" void kernel_launch(void* const* d_in, const int* in_sizes, int n_in,
                              void* d_out, int out_size, void* d_ws, size_t ws_size,
                              hipStream_t stream) {
    const float* boxes  = (const float*)d_in[0];
    const float* scores = (const float*)d_in[1];
    int n = in_sizes[0] / 7;           // 4096
    int words = (n + 63) >> 6;         // 64

    char* ws = (char*)d_ws;
    size_t off = 0;
    u64* adjC = (u64*)(ws + off);
    off += (size_t)n * words * sizeof(u64);
    unsigned char* occByte = (unsigned char*)(ws + off); off += 64 * 64;
    u64* SG     = (u64*)(ws + off); off += 64 * sizeof(u64);
    int* seedList = (int*)(ws + off); off += (size_t)n * sizeof(int);
    int* indices  = (int*)(ws + off); off += (size_t)n * sizeof(int);
    float* fused  = (float*)(ws + off); off += (size_t)n * 7 * sizeof(float);
    float* sfused = (float*)(ws + off); off += (size_t)n * sizeof(float);
    int* validArr = (int*)(ws + off); off += (size_t)n * sizeof(int);
    int* nclust   = (int*)(ws + off); off += sizeof(int);

    dim3 adjGrid(words, (n + 255) / 256);
    adj_kernel<<<adjGrid, 256, 0, stream>>>(boxes, adjC, occByte, validArr, n, words);
    mis_round_kernel<<<1, 1024, 0, stream>>>(adjC, occByte, SG, n, words);
    indices_kernel<<<(n + 63) / 64, 64, 0, stream>>>(adjC, occByte, SG, indices,
                                                     seedList, nclust, n, words);
    fusion_kernel<<<512, 64, 0, stream>>>(boxes, scores, indices, seedList, nclust,
                                          adjC, fused, sfused, validArr, n, words);
    finalize_kernel<<<1, 1024, 0, stream>>>(fused, sfused, validArr, indices,
                                            (float*)d_out, n);
}

// Round 23
// 80.584 us; speedup vs baseline: 1.1532x; 1.1532x over previous
//
#include <hip/hip_runtime.h>
#include <math.h>

#define PI_F      3.141592653f
#define TWO_PI_F  6.283185306f
#define HALF_PI_F 1.5707963265f
#define IOU_THR_F 0.1f

typedef unsigned long long u64;

__device__ __forceinline__ float limit_period_f(float v) {
    return v - floorf(v / TWO_PI_F + 0.5f) * TWO_PI_F;
}

// ---------------- Kernel 1: adjacency + occByte + validArr zero-init ----------
__global__ void adj_kernel(const float* __restrict__ boxes,
                           u64* __restrict__ adjC,
                           unsigned char* __restrict__ occByte,
                           int* __restrict__ validArr,
                           int n, int words) {
    __shared__ float jS[7][64];
    int w = blockIdx.x;
    int tid = threadIdx.x;              // 256 = 4 waves
    int lane = tid & 63, wv = tid >> 6;
    if (blockIdx.x == 0) {
        int i2 = blockIdx.y * 256 + tid;
        if (i2 < n) validArr[i2] = 0;
    }
    if (tid < 64) {
        int j = (w << 6) + tid;
        if (j < n) {
            float b0 = boxes[j*7+0], b1 = boxes[j*7+1], b2 = boxes[j*7+2];
            float b3 = boxes[j*7+3], b4 = boxes[j*7+4], b5 = boxes[j*7+5];
            jS[0][tid] = b0 - b5*0.5f;  jS[3][tid] = b0 + b5*0.5f;
            jS[1][tid] = b1 - b4*0.5f;  jS[4][tid] = b1 + b4*0.5f;
            jS[2][tid] = b2 - b3*0.5f;  jS[5][tid] = b2 + b3*0.5f;
            jS[6][tid] = (b5*b4)*b3;
        }
    }
    __syncthreads();
    int i = blockIdx.y * 256 + tid;
    u64 word = 0ull;
    if (i < n) {
        float b0 = boxes[i*7+0], b1 = boxes[i*7+1], b2 = boxes[i*7+2];
        float b3 = boxes[i*7+3], b4 = boxes[i*7+4], b5 = boxes[i*7+5];
        float lix = b0 - b5*0.5f, hix = b0 + b5*0.5f;
        float liy = b1 - b4*0.5f, hiy = b1 + b4*0.5f;
        float liz = b2 - b3*0.5f, hiz = b2 + b3*0.5f;
        float vi  = (b5*b4)*b3;
        int jmax = n - (w << 6); if (jmax > 64) jmax = 64;
        for (int jj = 0; jj < jmax; ++jj) {
            float ix = fminf(hix, jS[3][jj]) - fmaxf(lix, jS[0][jj]); ix = fmaxf(ix, 0.0f);
            float iy = fminf(hiy, jS[4][jj]) - fmaxf(liy, jS[1][jj]); iy = fmaxf(iy, 0.0f);
            float iz = fminf(hiz, jS[5][jj]) - fmaxf(liz, jS[2][jj]); iz = fmaxf(iz, 0.0f);
            float inter = (ix*iy)*iz;
            float u = fmaxf(vi + jS[6][jj] - inter, 1e-8f);
            bool pred = (inter / u) > IOU_THR_F;
            word |= ((u64)(pred ? 1 : 0)) << jj;
        }
        adjC[(size_t)w * n + i] = word;
    }
    u64 bal = __ballot((i < n) && word != 0ull);
    int rb = blockIdx.y * 4 + wv;
    if (lane == 0 && rb < 64)
        occByte[rb * 64 + w] = bal ? (unsigned char)1 : (unsigned char)0;
}

// ---------------- Kernel 2: per-node row-cache prep (multi-block, coalesced) --
__global__ __launch_bounds__(64) void prep_kernel(
        const u64* __restrict__ adjC,
        const unsigned char* __restrict__ occByte,
        u64* __restrict__ cRow, unsigned* __restrict__ idPack,
        u64* __restrict__ restM, int n, int words) {
    int rb = blockIdx.x;           // 64 row-blocks
    int lane = threadIdx.x;        // 64
    int i = (rb << 6) + lane;
    unsigned char ob = occByte[rb * 64 + lane];
    u64 occR = __ballot(ob != 0);  // occupied words for this row-block (uniform)
    unsigned pack = 0xFFFFFFFFu;
    u64 rest = 0ull;
    u64 r0 = 0ull, r1 = 0ull, r2 = 0ull, r3 = 0ull;
    int cnt = 0;
    if (i < n) {
        u64 oc = occR;
        while (oc) {
            int e = (int)__ffsll(oc) - 1; oc &= oc - 1;
            if (e >= words) break;
            u64 row = adjC[(size_t)e * n + i];    // coalesced across lanes
            if (row) {
                if      (cnt == 0) { r0 = row; pack = (pack & 0xFFFFFF00u) | (unsigned)e; }
                else if (cnt == 1) { r1 = row; pack = (pack & 0xFFFF00FFu) | ((unsigned)e << 8); }
                else if (cnt == 2) { r2 = row; pack = (pack & 0xFF00FFFFu) | ((unsigned)e << 16); }
                else if (cnt == 3) { r3 = row; pack = (pack & 0x00FFFFFFu) | ((unsigned)e << 24); }
                else rest |= 1ull << e;
                ++cnt;
            }
        }
    }
    if (i < n) {
        cRow[(size_t)0 * n + i] = r0;
        cRow[(size_t)1 * n + i] = r1;
        cRow[(size_t)2 * n + i] = r2;
        cRow[(size_t)3 * n + i] = r3;
        idPack[i] = pack;
        restM[i]  = rest;
    }
}

// ---------------- Kernel 3: Jacobi fixpoint rounds only (1 block) -------------
__global__ __launch_bounds__(1024) void mis_round_kernel(
        const u64* __restrict__ adjC,
        const u64* __restrict__ cRow, const unsigned* __restrict__ idPack,
        const u64* __restrict__ restM,
        u64* __restrict__ SG, int n, int words) {
    __shared__ u64 S_l[64], R_l[64];
    __shared__ int unresolved;
    int tid = threadIdx.x;              // 1024 = 16 waves
    int lane = tid & 63;

    if (tid < 64) {
        int base = tid << 6;
        int vb = n - base;
        u64 valid = (vb >= 64) ? ~0ull : ((vb <= 0) ? 0ull : ((1ull << vb) - 1ull));
        S_l[tid] = 0ull;
        R_l[tid] = ~valid;              // invalid tail = resolved nonseed
    }
    __syncthreads();

    // coalesced load burst of per-node cached data
    int id0[4], id1[4], id2[4], id3[4];
    u64 r0[4], r1[4], r2[4], r3[4], rstR[4];
    #pragma unroll
    for (int k = 0; k < 4; ++k) {
        int i = (k << 10) + tid;
        id0[k] = id1[k] = id2[k] = id3[k] = 0xFF;
        r0[k] = r1[k] = r2[k] = r3[k] = 0ull; rstR[k] = 0ull;
        if (i < n) {
            unsigned p = idPack[i];
            id0[k] = (int)(p & 0xFFu);
            id1[k] = (int)((p >> 8) & 0xFFu);
            id2[k] = (int)((p >> 16) & 0xFFu);
            id3[k] = (int)((p >> 24) & 0xFFu);
            r0[k] = cRow[(size_t)0 * n + i];
            r1[k] = cRow[(size_t)1 * n + i];
            r2[k] = cRow[(size_t)2 * n + i];
            r3[k] = cRow[(size_t)3 * n + i];
            int w_i = i >> 6;
            u64 inclm = (w_i >= 63) ? ~0ull : ((2ull << w_i) - 1ull);
            rstR[k] = restM[i] & inclm;   // only earlier-or-same words matter
        }
    }

    unsigned done = 0;
    #pragma unroll
    for (int k = 0; k < 4; ++k)
        if (((k << 10) + tid) >= n) done |= 1u << k;

    for (;;) {
        if (tid == 0) unresolved = 0;
        unsigned pendSeed = 0, pendRes = 0;
        #pragma unroll
        for (int k = 0; k < 4; ++k) {
            if (done & (1u << k)) continue;
            int i = (k << 10) + tid;
            int w_i = i >> 6, b_i = i & 63;
            u64 lowm = b_i ? ((1ull << b_i) - 1ull) : 0ull;
            u64 sA = 0ull, uA = 0ull;
            #define RACC(IDV, RV) if (IDV != 0xFF && IDV <= w_i) { \
                u64 em = (IDV < w_i) ? ~0ull : lowm; \
                u64 mr = (RV) & em; \
                sA |= mr & S_l[IDV]; uA |= mr & ~R_l[IDV]; }
            RACC(id0[k], r0[k]) RACC(id1[k], r1[k])
            RACC(id2[k], r2[k]) RACC(id3[k], r3[k])
            #undef RACC
            u64 rm = rstR[k];
            while (rm) {
                int e = (int)__ffsll(rm) - 1; rm &= rm - 1;
                u64 row = adjC[(size_t)e * n + i];
                u64 em = (e < w_i) ? ~0ull : lowm;
                sA |= row & S_l[e] & em;
                uA |= row & ~R_l[e] & em;
            }
            if (sA) pendRes |= 1u << k;
            else if (!uA) { pendSeed |= 1u << k; pendRes |= 1u << k; }
        }
        __syncthreads();
        #pragma unroll
        for (int k = 0; k < 4; ++k) {
            u64 bS = __ballot((pendSeed >> k) & 1u);
            u64 bR = __ballot((pendRes  >> k) & 1u);
            int w_i = ((k << 10) + tid) >> 6;
            if (lane == 0 && w_i < 64) {
                if (bS) atomicOr(&S_l[w_i], bS);
                if (bR) atomicOr(&R_l[w_i], bR);
            }
        }
        done |= pendRes;
        if ((done & 0xFu) != 0xFu) unresolved = 1;
        __syncthreads();
        if (unresolved == 0) break;
    }
    if (tid < 64) SG[tid] = S_l[tid];
}

// ---------------- Kernel 4: indices + seedList + nclust (multi-block) ---------
__global__ __launch_bounds__(64) void indices_kernel(
        const u64* __restrict__ adjC,
        const u64* __restrict__ SG,
        const u64* __restrict__ cRow, const unsigned* __restrict__ idPack,
        const u64* __restrict__ restM,
        int* __restrict__ indices, int* __restrict__ seedList,
        int* __restrict__ nclust, int n, int words) {
    __shared__ u64 S_s[64];
    __shared__ int ws_s[64];
    int lane = threadIdx.x;        // 64 = 1 wave
    u64 s = (lane < words) ? SG[lane] : 0ull;
    S_s[lane] = s;
    int pc = (int)__popcll(s);
    int x = pc;
    for (int o = 1; o < 64; o <<= 1) {
        int y = __shfl_up(x, o);
        if (lane >= o) x += y;
    }
    ws_s[lane] = x - pc;           // exclusive scan
    if (blockIdx.x == 0 && lane == 63) *nclust = x;
    __syncthreads();
    int i = blockIdx.x * 64 + lane;
    if (i >= n) return;
    unsigned p = idPack[i];
    u64 c0 = cRow[(size_t)0 * n + i];
    u64 c1 = cRow[(size_t)1 * n + i];
    u64 c2 = cRow[(size_t)2 * n + i];
    u64 c3 = cRow[(size_t)3 * n + i];
    int best = -1;
    // overflow words are higher than cached ids: scan descending first
    u64 rm = restM[i];
    while (rm) {
        int e = 63 - (int)__clzll(rm); rm &= ~(1ull << e);
        u64 s2 = adjC[(size_t)e * n + i] & S_s[e];
        if (s2) { best = (e << 6) + 63 - (int)__clzll(s2); break; }
    }
    if (best < 0) {
        #define ITRY(IDV, CV) if (best < 0 && (IDV) != 0xFFu) { \
            int e = (int)(IDV); \
            u64 s2 = (CV) & S_s[e]; \
            if (s2) best = (e << 6) + 63 - (int)__clzll(s2); }
        ITRY((p >> 24) & 0xFFu, c3)
        ITRY((p >> 16) & 0xFFu, c2)
        ITRY((p >> 8) & 0xFFu, c1)
        ITRY(p & 0xFFu, c0)
        #undef ITRY
    }
    int idx = 0;
    if (best >= 0) {
        int w2 = best >> 6, b = best & 63;
        u64 incl = (b >= 63) ? ~0ull : ((2ull << b) - 1ull);
        idx = ws_s[w2] + (int)__popcll(S_s[w2] & incl);   // 1-based cid
    }
    indices[i] = idx;
    int wj = i >> 6, bj = i & 63;
    if ((S_s[wj] >> bj) & 1ull) {
        int rank = ws_s[wj] + (int)__popcll(S_s[wj] & (bj ? ((1ull << bj) - 1ull) : 0ull)) + 1;
        seedList[rank - 1] = i;
    }
}

// ---------------- Kernel 5: per-cluster fusion (LDS-staged, phase-split) ------
// Loops only over real clusters (i < nclust); rows >= nclust need nothing:
// validArr zero-initialized in adj, and finalize gates all reads on validS.
__global__ void fusion_kernel(const float* __restrict__ boxes,
                              const float* __restrict__ scores,
                              const int* __restrict__ indices,
                              const int* __restrict__ seedListG,
                              const int* __restrict__ nclust,
                              const u64* __restrict__ adjC,
                              float* __restrict__ fused,
                              float* __restrict__ sfused,
                              int* __restrict__ validArr, int n, int words) {
    int lane = threadIdx.x;       // 64 = 1 wave
    int nc = *nclust;
    __shared__ unsigned short js[256];
    __shared__ float ms[256];
    __shared__ float ds[256];
    __shared__ float bx[6][256];
    __shared__ float sv[256], cv[256], pw[256];
    __shared__ float refdirS, denomS;
    __shared__ int   flipS;
    for (int i = blockIdx.x; i < nc; i += gridDim.x) {
        int cid = i + 1;
        int s = seedListG[i];
        u64 bits = (lane < words) ? adjC[(size_t)lane * n + s] : 0ull;
        // filter: keep only nodes whose final cluster is cid
        u64 keep = 0ull;
        u64 t = bits;
        while (t) {
            int b = (int)__ffsll(t) - 1;
            t &= t - 1;
            int node = (lane << 6) + b;
            if (indices[node] == cid) keep |= (1ull << b);
        }
        int cnt = __popcll(keep);
        int x = cnt;
        for (int o = 1; o < 64; o <<= 1) {
            int y = __shfl_up(x, o);
            if (lane >= o) x += y;
        }
        int excl = x - cnt;
        int m = __shfl(x, 63);
        int pos = excl;
        t = keep;
        while (t) {
            int b = (int)__ffsll(t) - 1;
            t &= t - 1;
            js[pos++] = (unsigned short)((lane << 6) + b);
        }
        __syncthreads();
        for (int k = lane; k < m; k += 64) {
            int j = js[k];
            ms[k] = scores[j];
            ds[k] = limit_period_f(boxes[j*7+6]);
            bx[0][k] = boxes[j*7+0];
            bx[1][k] = boxes[j*7+1];
            bx[2][k] = boxes[j*7+2];
            bx[3][k] = boxes[j*7+3];
            bx[4][k] = boxes[j*7+4];
            bx[5][k] = boxes[j*7+5];
        }
        __syncthreads();
        if (m == 0) {
            if (lane == 0) {
                for (int k = 0; k < 7; ++k) fused[i*7+k] = 0.0f;
                sfused[i] = 0.0f; validArr[i] = 0;
            }
            __syncthreads();
            continue;
        }
        // ---- phase A (lane 0, LDS-only): ssum/argmax/refdir/denom/flip ----
        if (lane == 0) {
            float ssum = 0.0f, smax = -1e30f; int kref = 0;
            for (int k = 0; k < m; ++k) {
                float sc = ms[k];
                ssum += sc;
                if (sc > smax) { smax = sc; kref = k; }
            }
            float refdir = ds[kref];
            float denom = fmaxf(ssum, 1e-12f);
            float sgt = 0.0f;
            for (int k = 0; k < m; ++k) {
                float d = fabsf(ds[k] - refdir);
                if (d > PI_F) d = TWO_PI_F - d;
                if (d > HALF_PI_F) sgt += ms[k];
            }
            float sle = ssum - sgt;
            refdirS = refdir; denomS = denom;
            flipS = (sgt <= sle) ? 1 : 0;
        }
        __syncthreads();
        // ---- phase B (parallel): per-element trig ----
        {
            float refdir = refdirS, denom = denomS;
            bool flipGt = flipS != 0;
            for (int k = lane; k < m; k += 64) {
                float dj = ds[k];
                float d = fabsf(dj - refdir);
                if (d > PI_F) d = TWO_PI_F - d;
                bool gt = d > HALF_PI_F;
                bool flip = flipGt ? gt : !gt;
                float adj_d = limit_period_f(dj + (flip ? PI_F : 0.0f));
                float wgt = ms[k] / denom;
                sv[k] = sinf(adj_d) * wgt;
                cv[k] = cosf(adj_d) * wgt;
            }
        }
        __syncthreads();
        // ---- phase C (lane 0): weighted sums + theta + sort ----
        if (lane == 0) {
            float denom = denomS;
            float cd0=0,cd1=0,cd2=0,cd3=0,cd4=0,cd5=0;
            for (int k = 0; k < m; ++k) {
                float wgt = ms[k] / denom;
                cd0 += wgt * bx[0][k];
                cd1 += wgt * bx[1][k];
                cd2 += wgt * bx[2][k];
                cd3 += wgt * bx[3][k];
                cd4 += wgt * bx[4][k];
                cd5 += wgt * bx[5][k];
            }
            float ssin = 0.0f, scos = 0.0f;
            for (int k = 0; k < m; ++k) { ssin += sv[k]; scos += cv[k]; }
            float theta = atan2f(ssin, scos);
            for (int k = 1; k < m; ++k) {
                float key = ms[k]; int p = k - 1;
                while (p >= 0 && ms[p] < key) { ms[p+1] = ms[p]; --p; }
                ms[p+1] = key;
            }
            bx[0][255] = cd0; bx[1][255] = cd1; bx[2][255] = cd2;
            bx[3][255] = cd3; bx[4][255] = cd4; bx[5][255] = cd5;
            sv[255] = theta;
        }
        __syncthreads();
        // ---- phase D (parallel): powf on sorted scores ----
        for (int k = lane; k < m; k += 64)
            pw[k] = powf(ms[k], (float)(k+1));
        __syncthreads();
        // ---- phase E (lane 0): s_fused + corners + writes ----
        if (lane == 0) {
            float cd0 = bx[0][255], cd1 = bx[1][255], cd2 = bx[2][255];
            float cd3 = bx[3][255], cd4 = bx[4][255], cd5 = bx[5][255];
            float theta = sv[255];
            float sf = 0.0f;
            for (int k = 0; k < m; ++k) sf += pw[k];
            sf = fminf(sf, 1.0f);
            float c_ = cosf(theta), s_ = sinf(theta);
            float wdim = cd4, ldim = cd5;
            const float xs[4]  = {0.5f, 0.5f, -0.5f, -0.5f};
            const float ys_[4] = {-0.5f, 0.5f, 0.5f, -0.5f};
            bool inr = true;
            for (int c = 0; c < 4; ++c) {
                float cx = ldim * xs[c], cy = wdim * ys_[c];
                float rx = cx*c_ - cy*s_ + cd0;
                float ry = cx*s_ + cy*c_ + cd1;
                inr = inr && (rx > -140.8f) && (rx < 140.8f) && (ry > -40.0f) && (ry < 40.0f);
            }
            fused[i*7+0]=cd0; fused[i*7+1]=cd1; fused[i*7+2]=cd2;
            fused[i*7+3]=cd3; fused[i*7+4]=cd4; fused[i*7+5]=cd5;
            fused[i*7+6]=theta;
            sfused[i] = sf;
            validArr[i] = inr ? 1 : 0;
        }
        __syncthreads();
    }
}

// ---------------- Kernel 6: cumsum + gated output writes ----------------
__global__ void finalize_kernel(const float* __restrict__ fused,
                                const float* __restrict__ sfused,
                                const int* __restrict__ validArr,
                                const int* __restrict__ indices,
                                float* __restrict__ out, int n) {
    __shared__ int newidS[4096];
    __shared__ unsigned char validS[4096];
    __shared__ int scanBuf[1024];
    int tid = threadIdx.x;  // 1024
    int per = (n + 1023) >> 10;  // 4
    int base = tid * per;
    int v[8];
    int sum = 0;
    for (int k = 0; k < per && k < 8; ++k) {
        int j = base + k;
        int vv = (j < n) ? validArr[j] : 0;
        v[k] = vv; sum += vv;
    }
    scanBuf[tid] = sum;
    __syncthreads();
    for (int o = 1; o < 1024; o <<= 1) {
        int val = scanBuf[tid];
        int add = (tid >= o) ? scanBuf[tid - o] : 0;
        __syncthreads();
        scanBuf[tid] = val + add;
        __syncthreads();
    }
    int run = scanBuf[tid] - sum;
    for (int k = 0; k < per && k < 8; ++k) {
        int j = base + k;
        if (j < n) { run += v[k]; newidS[j] = run; validS[j] = (unsigned char)v[k]; }
    }
    __syncthreads();
    float* boxesO  = out;
    float* scoresO = out + (size_t)7*n;
    float* validO  = out + (size_t)8*n;
    float* idxO    = out + (size_t)9*n;
    for (int j = tid; j < n; j += 1024) {
        int vv = validS[j];
        #pragma unroll
        for (int k = 0; k < 7; ++k)
            boxesO[j*7+k] = vv ? fused[j*7+k] : 0.0f;
        scoresO[j] = vv ? sfused[j] : 0.0f;
        validO[j]  = vv ? 1.0f : 0.0f;
        int ind = indices[j];
        int safe = ind - 1; if (safe < 0) safe = 0;
        bool nv = (ind > 0) && (validS[safe] != 0);
        idxO[j] = nv ? (float)newidS[safe] : 0.0f;
    }
}

extern "C" void kernel_launch(void* const* d_in, const int* in_sizes, int n_in,
                              void* d_out, int out_size, void* d_ws, size_t ws_size,
                              hipStream_t stream) {
    const float* boxes  = (const float*)d_in[0];
    const float* scores = (const float*)d_in[1];
    int n = in_sizes[0] / 7;           // 4096
    int words = (n + 63) >> 6;         // 64

    char* ws = (char*)d_ws;
    size_t off = 0;
    u64* adjC = (u64*)(ws + off);
    off += (size_t)n * words * sizeof(u64);
    unsigned char* occByte = (unsigned char*)(ws + off); off += 64 * 64;
    u64* cRow   = (u64*)(ws + off); off += (size_t)4 * n * sizeof(u64);
    unsigned* idPack = (unsigned*)(ws + off); off += (size_t)n * sizeof(unsigned);
    u64* restM  = (u64*)(ws + off); off += (size_t)n * sizeof(u64);
    u64* SG     = (u64*)(ws + off); off += 64 * sizeof(u64);
    int* seedList = (int*)(ws + off); off += (size_t)n * sizeof(int);
    int* indices  = (int*)(ws + off); off += (size_t)n * sizeof(int);
    float* fused  = (float*)(ws + off); off += (size_t)n * 7 * sizeof(float);
    float* sfused = (float*)(ws + off); off += (size_t)n * sizeof(float);
    int* validArr = (int*)(ws + off); off += (size_t)n * sizeof(int);
    int* nclust   = (int*)(ws + off); off += sizeof(int);

    dim3 adjGrid(words, (n + 255) / 256);
    adj_kernel<<<adjGrid, 256, 0, stream>>>(boxes, adjC, occByte, validArr, n, words);
    prep_kernel<<<64, 64, 0, stream>>>(adjC, occByte, cRow, idPack, restM, n, words);
    mis_round_kernel<<<1, 1024, 0, stream>>>(adjC, cRow, idPack, restM, SG, n, words);
    indices_kernel<<<(n + 63) / 64, 64, 0, stream>>>(adjC, SG, cRow, idPack, restM,
                                                     indices, seedList, nclust, n, words);
    fusion_kernel<<<512, 64, 0, stream>>>(boxes, scores, indices, seedList, nclust,
                                          adjC, fused, sfused, validArr, n, words);
    finalize_kernel<<<1, 1024, 0, stream>>>(fused, sfused, validArr, indices,
                                            (float*)d_out, n);
}